// Round 15
// baseline (522.640 us; speedup 1.0000x reference)
//
#include <hip/hip_runtime.h>
#include <hip/hip_cooperative_groups.h>

namespace cg = cooperative_groups;

typedef unsigned short u16;
typedef __attribute__((ext_vector_type(8))) short short8;
typedef __attribute__((ext_vector_type(4))) float f32x4;

#define D_DIM   1024
#define ROWS    32768   // B*T = 4*8192
#define T_DIM   8192

__device__ __forceinline__ float bf2f(u16 u) {
    union { unsigned int i; float f; } c; c.i = ((unsigned int)u) << 16; return c.f;
}
__device__ __forceinline__ u16 f2bf(float f) {
    union { float f; unsigned int i; } c; c.f = f;
    unsigned int r = c.i + 0x7FFF + ((c.i >> 16) & 1);   // RNE
    return (u16)(r >> 16);
}

#define GLL16(gp, lp) \
    __builtin_amdgcn_global_load_lds((const __attribute__((address_space(1))) void*)(gp), \
                                     (__attribute__((address_space(3))) void*)(lp), 16, 0, 0)

// ---- GEMM slot macro: EXACT r4/r9/r13 structure (session best; schedule frozen) ----
#define SLOT(RING, SRING, STG, VM) do {                                           \
    short8 bF[4], aF[8];                                                          \
    _Pragma("unroll")                                                             \
    for (int nt = 0; nt < 4; ++nt)                                                \
        bF[nt] = *reinterpret_cast<const short8*>(&b_sh[RING][bRd + nt * 512]);   \
    _Pragma("unroll")                                                             \
    for (int mi = 0; mi < 8; ++mi)                                                \
        aF[mi] = *reinterpret_cast<const short8*>(&a_sh[RING][aRd + mi * 512]);   \
    if (STG) {                                                                    \
        GLL16(aPtr0, &a_sh[SRING][aDst0]); GLL16(aPtr1, &a_sh[SRING][aDst1]);     \
        GLL16(bPtr0, &b_sh[SRING][aDst0]); GLL16(bPtr1, &b_sh[SRING][aDst1]);     \
        aPtr0 += 32; aPtr1 += 32; bPtr0 += 32; bPtr1 += 32;                       \
    }                                                                             \
    _Pragma("unroll")                                                             \
    for (int mi = 0; mi < 8; ++mi)                                                \
        _Pragma("unroll")                                                         \
        for (int nt = 0; nt < 4; ++nt)                                            \
            acc[mi][nt] = __builtin_amdgcn_mfma_f32_16x16x32_bf16(                \
                aF[mi], bF[nt], acc[mi][nt], 0, 0, 0);                            \
    __builtin_amdgcn_sched_barrier(0);                                            \
    if ((VM) == 8)      asm volatile("s_waitcnt vmcnt(8)" ::: "memory");          \
    else if ((VM) == 4) asm volatile("s_waitcnt vmcnt(4)" ::: "memory");          \
    else if ((VM) == 0) asm volatile("s_waitcnt vmcnt(0)" ::: "memory");          \
    __builtin_amdgcn_s_barrier();                                                 \
} while (0)

// ---------------- Single persistent cooperative kernel ----------------
// 256 blocks x 512 thr = exactly 1 block/CU (128 KiB LDS) -> full co-residency.
// Phase P: x fp32->bf16 (grid-stride x32) | W transpose (2 tiles/pass x6, LDS reuse)
//          | zero qssq|kssq|kv (278,528 B).                    grid.sync()
// Phase G: r13 GEMM body looped over 6 tiles (flat = i*256+blk keeps the XCD-swizzle
//          cohorts under round-robin block->XCD). Per-CU serialization identical to
//          the 1536-block launch (only 1 block/CU was ever resident).  grid.sync()
// Phase R: kv_reduce (1024 units of 32 rows x 128 lanes).      grid.sync()
// Phase F: finalize (grid-stride x32). out overwrites xb/WT (dead after phase G).
__global__ __launch_bounds__(512, 1)
void hydra(const float* x, const float* W, const float* bqkv,
           const float* scale, const float* bias,
           u16* xb, u16* WT, u16* qb, u16* pb,
           float* qssq, float* kssq, float* kv, float* out)
{
    cg::grid_group grid = cg::this_grid();
    const int tid = threadIdx.x;
    const int blk = blockIdx.x;    // 0..255

    // 4-slot ring: each slot 256 rows x 32 k (u16) = 16 KB per operand; 128 KiB total
    __shared__ __align__(16) u16 a_sh[4][8192];
    __shared__ __align__(16) u16 b_sh[4][8192];

    const size_t g = (size_t)blk * 512 + tid;   // 0..131071

    // ================= Phase P: prep =================
    {
        // x convert: 4,194,304 vec8 units / 131072 threads = 32 per thread
        #pragma unroll 1
        for (int r = 0; r < 32; ++r) {
            size_t idx = (g + (size_t)r * 131072) * 8;
            float4 f0 = *reinterpret_cast<const float4*>(x + idx);
            float4 f1 = *reinterpret_cast<const float4*>(x + idx + 4);
            short8 v;
            v[0] = (short)f2bf(f0.x); v[1] = (short)f2bf(f0.y);
            v[2] = (short)f2bf(f0.z); v[3] = (short)f2bf(f0.w);
            v[4] = (short)f2bf(f1.x); v[5] = (short)f2bf(f1.y);
            v[6] = (short)f2bf(f1.z); v[7] = (short)f2bf(f1.w);
            *reinterpret_cast<short8*>(xb + idx) = v;
        }
        // W transpose: 3072 32x32 tiles; 2 tiles per pass (512 thr), 6 passes
        const int sub = tid >> 8;      // 0..1
        const int t   = tid & 255;
        const int tx  = t & 31;
        const int ty  = t >> 5;
        u16* tl = &a_sh[0][0] + sub * 1152;     // 32*34=1088 u16 per tile, padded
        #pragma unroll 1
        for (int pass = 0; pass < 6; ++pass) {
            int q  = blk * 12 + pass * 2 + sub;   // 0..3071
            int nb = (q % 96) * 32;
            int kb = (q / 96) * 32;
            #pragma unroll
            for (int i = 0; i < 32; i += 8)
                tl[(ty + i) * 34 + tx] = f2bf(W[(size_t)(kb + ty + i) * 3072 + nb + tx]);
            __syncthreads();
            #pragma unroll
            for (int i = 0; i < 32; i += 8)
                WT[(size_t)(nb + ty + i) * D_DIM + kb + tx] = tl[tx * 34 + ty + i];
            __syncthreads();
        }
        // zero qssq|kssq|kv: 278,528 B contiguous = 17408 float4
        if (g < 17408) {
            float4 z4 = make_float4(0.f, 0.f, 0.f, 0.f);
            *reinterpret_cast<float4*>(qssq + g * 4) = z4;
        }
    }
    grid.sync();

    // ================= Phase G: GEMM (6 tiles per block) =================
    {
        const int lane = tid & 63;
        const int w    = tid >> 6;      // wave 0..7
        const int l15  = lane & 15;
        const int quad = lane >> 4;     // 0..3
        const int wm   = w >> 2;        // 0..1  (M half)
        const int wn   = w & 3;         // 0..3  (N quarter)
        const int row0 = w * 32 + (lane >> 2);
        const int gsrc = (lane & 3) ^ ((lane >> 3) & 3);
        const int aDst0 = w * 1024;
        const int aDst1 = w * 1024 + 512;
        const int gq  = (quad ^ ((l15 >> 1) & 3)) * 8;
        const int aRd = (wm * 128 + l15) * 32 + gq;
        const int bRd = (wn * 64 + l15) * 32 + gq;

        #pragma unroll 1
        for (int i = 0; i < 6; ++i) {
            const int flat = i * 256 + blk;
            const int swz  = (flat & 7) * 192 + (flat >> 3);
            const int bx   = swz & 127;
            const int by   = swz >> 7;
            const int r0   = bx * 256;
            const int c0   = by * 256;
            const int K0   = 1024 + (by - 4) * 128;
            const int V0   = K0 + 1024;

            const u16* aPtr0 = xb + (size_t)(r0 + row0) * D_DIM + gsrc * 8;
            const u16* aPtr1 = xb + (size_t)(r0 + row0 + 16) * D_DIM + gsrc * 8;
            int srcB0, srcB1;
            if (by < 4) {
                srcB0 = c0 + row0;
                srcB1 = c0 + row0 + 16;
            } else {
                int rB0 = row0,      wn0 = rB0 >> 6, cs0 = rB0 & 63;
                int rB1 = row0 + 16, wn1 = rB1 >> 6, cs1 = rB1 & 63;
                srcB0 = (cs0 < 32) ? (K0 + wn0 * 32 + cs0) : (V0 + wn0 * 32 + cs0 - 32);
                srcB1 = (cs1 < 32) ? (K0 + wn1 * 32 + cs1) : (V0 + wn1 * 32 + cs1 - 32);
            }
            const u16* bPtr0 = WT + (size_t)srcB0 * D_DIM + gsrc * 8;
            const u16* bPtr1 = WT + (size_t)srcB1 * D_DIM + gsrc * 8;

            f32x4 acc[8][4];
            #pragma unroll
            for (int mi = 0; mi < 8; ++mi)
                #pragma unroll
                for (int nt = 0; nt < 4; ++nt) acc[mi][nt] = (f32x4)(0.0f);

            // prologue: stage slots 0,1,2
            GLL16(aPtr0, &a_sh[0][aDst0]); GLL16(aPtr1, &a_sh[0][aDst1]);
            GLL16(bPtr0, &b_sh[0][aDst0]); GLL16(bPtr1, &b_sh[0][aDst1]);
            aPtr0 += 32; aPtr1 += 32; bPtr0 += 32; bPtr1 += 32;
            GLL16(aPtr0, &a_sh[1][aDst0]); GLL16(aPtr1, &a_sh[1][aDst1]);
            GLL16(bPtr0, &b_sh[1][aDst0]); GLL16(bPtr1, &b_sh[1][aDst1]);
            aPtr0 += 32; aPtr1 += 32; bPtr0 += 32; bPtr1 += 32;
            GLL16(aPtr0, &a_sh[2][aDst0]); GLL16(aPtr1, &a_sh[2][aDst1]);
            GLL16(bPtr0, &b_sh[2][aDst0]); GLL16(bPtr1, &b_sh[2][aDst1]);
            aPtr0 += 32; aPtr1 += 32; bPtr0 += 32; bPtr1 += 32;
            asm volatile("s_waitcnt vmcnt(8)" ::: "memory");
            __builtin_amdgcn_s_barrier();

            #pragma unroll 1
            for (int it = 0; it < 7; ++it) {
                SLOT(0, 3, 1, 8);
                SLOT(1, 0, 1, 8);
                SLOT(2, 1, 1, 8);
                SLOT(3, 2, 1, 8);
            }
            SLOT(0, 3, 1, 8);
            SLOT(1, 0, 0, 4);
            SLOT(2, 0, 0, 0);
            SLOT(3, 0, 0, -1);

            if (by < 4) {
                float bcol[4];
                #pragma unroll
                for (int nt = 0; nt < 4; ++nt)
                    bcol[nt] = bqkv[c0 + wn * 64 + nt * 16 + l15];
                #pragma unroll
                for (int mi = 0; mi < 8; ++mi)
                    #pragma unroll
                    for (int nt = 0; nt < 4; ++nt)
                        #pragma unroll
                        for (int rg = 0; rg < 4; ++rg) acc[mi][nt][rg] += bcol[nt];

                #pragma unroll
                for (int mi = 0; mi < 8; ++mi)
                    #pragma unroll
                    for (int rg = 0; rg < 4; ++rg) {
                        float s = acc[mi][0][rg] * acc[mi][0][rg]
                                + acc[mi][1][rg] * acc[mi][1][rg]
                                + acc[mi][2][rg] * acc[mi][2][rg]
                                + acc[mi][3][rg] * acc[mi][3][rg];
                        #pragma unroll
                        for (int m = 1; m < 16; m <<= 1) s += __shfl_xor(s, m, 16);
                        if (l15 == 0)
                            atomicAdd(&qssq[r0 + wm * 128 + mi * 16 + quad * 4 + rg], s);
                    }

                #pragma unroll
                for (int mi = 0; mi < 8; ++mi)
                    #pragma unroll
                    for (int nt = 0; nt < 4; ++nt) {
                        int col = c0 + wn * 64 + nt * 16 + l15;
                        #pragma unroll
                        for (int rg = 0; rg < 4; ++rg) {
                            int row = r0 + wm * 128 + mi * 16 + quad * 4 + rg;
                            qb[(size_t)row * 1024 + col] = f2bf(acc[mi][nt][rg]);
                        }
                    }
            } else {
                float bcol[4];
                #pragma unroll
                for (int nt = 0; nt < 4; ++nt)
                    bcol[nt] = (nt < 2) ? bqkv[K0 + wn * 32 + nt * 16 + l15]
                                        : bqkv[V0 + wn * 32 + (nt - 2) * 16 + l15];
                #pragma unroll
                for (int mi = 0; mi < 8; ++mi)
                    #pragma unroll
                    for (int nt = 0; nt < 4; ++nt)
                        #pragma unroll
                        for (int rg = 0; rg < 4; ++rg) acc[mi][nt][rg] += bcol[nt];

                #pragma unroll
                for (int mi = 0; mi < 8; ++mi)
                    #pragma unroll
                    for (int rg = 0; rg < 4; ++rg) {
                        float s = acc[mi][0][rg] * acc[mi][0][rg]
                                + acc[mi][1][rg] * acc[mi][1][rg];
                        #pragma unroll
                        for (int m = 1; m < 16; m <<= 1) s += __shfl_xor(s, m, 16);
                        if (l15 == 0)
                            atomicAdd(&kssq[r0 + wm * 128 + mi * 16 + quad * 4 + rg], s);
                    }

                #pragma unroll
                for (int mi = 0; mi < 8; ++mi)
                    #pragma unroll
                    for (int ntp = 0; ntp < 2; ++ntp) {
                        int col = (by - 4) * 128 + wn * 32 + ntp * 16 + l15;
                        #pragma unroll
                        for (int rg = 0; rg < 4; ++rg) {
                            int row = r0 + wm * 128 + mi * 16 + quad * 4 + rg;
                            pb[(size_t)row * 1024 + col] =
                                f2bf(acc[mi][ntp][rg] * acc[mi][ntp + 2][rg]);
                        }
                    }
            }
            // LDS reuse across tiles is safe: the tail's last SLOT ends with
            // s_barrier, and the next tile's GLLs only overwrite after all waves
            // passed it (same WAR argument as the in-loop ring).
        }
    }
    grid.sync();

    // ================= Phase R: kv_reduce =================
    {
        int gthr = blk * 512 + tid;
        int dv   = (gthr & 127) * 8;
        int unit = gthr >> 7;            // 0..1023
        int b    = unit >> 8;            // 0..3
        int t0   = (unit & 255) * 32;
        float a[8];
        #pragma unroll
        for (int e = 0; e < 8; ++e) a[e] = 0.0f;
        #pragma unroll 1
        for (int r = 0; r < 32; ++r) {
            int row = b * T_DIM + t0 + r;
            float kin = rsqrtf(kssq[row]);
            short8 p8 = *reinterpret_cast<const short8*>(pb + (size_t)row * 1024 + dv);
            #pragma unroll
            for (int e = 0; e < 8; ++e)
                a[e] += bf2f((u16)p8[e]) * kin;
        }
        #pragma unroll
        for (int e = 0; e < 8; ++e)
            atomicAdd(&kv[b * D_DIM + dv + e], a[e]);
    }
    grid.sync();

    // ================= Phase F: finalize =================
    {
        #pragma unroll 1
        for (int r = 0; r < 32; ++r) {
            size_t idx = g + (size_t)r * 131072;   // vec8 index
            int row = (int)(idx >> 7);
            int dv  = ((int)idx & 127) * 8;
            int b   = row >> 13;
            float qi = rsqrtf(qssq[row]);
            short8 qv = *reinterpret_cast<const short8*>(qb + (size_t)row * D_DIM + dv);
            const float* kvp = kv + b * D_DIM + dv;
            const float* sp  = scale + dv;
            const float* bp  = bias + dv;
            float4 o0, o1;
            o0.x = bf2f((u16)qv[0]) * qi * kvp[0] * sp[0] + bp[0];
            o0.y = bf2f((u16)qv[1]) * qi * kvp[1] * sp[1] + bp[1];
            o0.z = bf2f((u16)qv[2]) * qi * kvp[2] * sp[2] + bp[2];
            o0.w = bf2f((u16)qv[3]) * qi * kvp[3] * sp[3] + bp[3];
            o1.x = bf2f((u16)qv[4]) * qi * kvp[4] * sp[4] + bp[4];
            o1.y = bf2f((u16)qv[5]) * qi * kvp[5] * sp[5] + bp[5];
            o1.z = bf2f((u16)qv[6]) * qi * kvp[6] * sp[6] + bp[6];
            o1.w = bf2f((u16)qv[7]) * qi * kvp[7] * sp[7] + bp[7];
            float* op = out + (size_t)row * D_DIM + dv;
            *reinterpret_cast<float4*>(op)     = o0;
            *reinterpret_cast<float4*>(op + 4) = o1;
        }
    }
}

extern "C" void kernel_launch(void* const* d_in, const int* in_sizes, int n_in,
                              void* d_out, int out_size, void* d_ws, size_t ws_size,
                              hipStream_t stream) {
    const float* x     = (const float*)d_in[0];
    const float* W     = (const float*)d_in[1];
    const float* bqkv  = (const float*)d_in[2];
    const float* scale = (const float*)d_in[3];
    const float* bias  = (const float*)d_in[4];
    float* out = (float*)d_out;

    // d_out doubles as scratch until phase F: xb (64 MB) + WT (6 MB) < 128 MB
    u16* xb = (u16*)d_out;
    u16* WT = (u16*)((char*)d_out + 67108864);

    char* ws = (char*)d_ws;
    u16*   qb   = (u16*)ws;                         //  67,108,864 B
    u16*   pb   = (u16*)(ws + 67108864);            //  67,108,864 B (k*v products)
    float* qssq = (float*)(ws + 134217728);         //     131,072 B
    float* kssq = (float*)(ws + 134348800);         //     131,072 B
    float* kv   = (float*)(ws + 134479872);         //      16,384 B
    // qssq|kssq|kv contiguous: 278,528 B zeroed in phase P

    void* args[] = {(void*)&x, (void*)&W, (void*)&bqkv, (void*)&scale, (void*)&bias,
                    (void*)&xb, (void*)&WT, (void*)&qb, (void*)&pb,
                    (void*)&qssq, (void*)&kssq, (void*)&kv, (void*)&out};
    hipLaunchCooperativeKernel((void*)hydra, dim3(256), dim3(512), args, 0, stream);
}

// Round 16
// 361.867 us; speedup vs baseline: 1.4443x; 1.4443x over previous
//
#include <hip/hip_runtime.h>

typedef unsigned short u16;
typedef __attribute__((ext_vector_type(8))) short short8;
typedef __attribute__((ext_vector_type(4))) float f32x4;

#define D_DIM   1024
#define ROWS    32768   // B*T = 4*8192
#define T_DIM   8192

__device__ __forceinline__ float bf2f(u16 u) {
    union { unsigned int i; float f; } c; c.i = ((unsigned int)u) << 16; return c.f;
}
__device__ __forceinline__ u16 f2bf(float f) {
    union { float f; unsigned int i; } c; c.f = f;
    unsigned int r = c.i + 0x7FFF + ((c.i >> 16) & 1);   // RNE
    return (u16)(r >> 16);
}

#define GLL16(gp, lp) \
    __builtin_amdgcn_global_load_lds((const __attribute__((address_space(1))) void*)(gp), \
                                     (__attribute__((address_space(3))) void*)(lp), 16, 0, 0)

// ---------------- Kernel 0 (fused prep): convert x, transpose W, zero accumulators ----
// blocks [0, 16384)           : x fp32 -> xb bf16 (vec8 per thread)
// blocks [16384, 16384+3072)  : Wqkv (1024x3072 fp32) -> WT (3072x1024 bf16) transpose
// blocks [19456, 19456+68)    : zero qssq|kssq|kv (278,528 B contiguous)
// All three independent; stream order guarantees completion before gemm_k.
// (r15's persistent-cooperative fusion of ALL phases was falsified: 522us vs 360 —
//  mega-kernel register liveness + cooperative overhead cost far more than the
//  ~30us of launch gaps it removed. Separate dispatches are structurally right.)
__global__ __launch_bounds__(256)
void prep(const float* __restrict__ x, u16* __restrict__ xb,
          const float* __restrict__ W, u16* __restrict__ WT,
          float* __restrict__ zbase)
{
    const int bid = blockIdx.x;
    const int tid = threadIdx.x;
    __shared__ u16 tile[32][34];

    if (bid < 16384) {
        size_t idx = ((size_t)bid * 256 + tid) * 8;
        float4 f0 = *reinterpret_cast<const float4*>(x + idx);
        float4 f1 = *reinterpret_cast<const float4*>(x + idx + 4);
        short8 v;
        v[0] = (short)f2bf(f0.x); v[1] = (short)f2bf(f0.y);
        v[2] = (short)f2bf(f0.z); v[3] = (short)f2bf(f0.w);
        v[4] = (short)f2bf(f1.x); v[5] = (short)f2bf(f1.y);
        v[6] = (short)f2bf(f1.z); v[7] = (short)f2bf(f1.w);
        *reinterpret_cast<short8*>(xb + idx) = v;
    } else if (bid < 16384 + 3072) {
        int q  = bid - 16384;
        int nb = (q % 96) * 32;
        int kb = (q / 96) * 32;
        int tx = tid & 31;    // 0..31
        int ty = tid >> 5;    // 0..7
        #pragma unroll
        for (int i = 0; i < 32; i += 8)
            tile[ty + i][tx] = f2bf(W[(size_t)(kb + ty + i) * 3072 + nb + tx]);
        __syncthreads();
        #pragma unroll
        for (int i = 0; i < 32; i += 8)
            WT[(size_t)(nb + ty + i) * D_DIM + kb + tx] = tile[tx][ty + i];
    } else {
        int z = bid - (16384 + 3072);              // 0..67
        float4 zero = make_float4(0.f, 0.f, 0.f, 0.f);
        *reinterpret_cast<float4*>(zbase + ((size_t)z * 256 + tid) * 4) = zero;
    }
}

// ---------------- Kernel 2: r4 GEMM structure + paired k/v column partition ----
// (Session best, reverified r13/r14: gemm ~257us, MfmaUtil ~35, 0 conflicts.)
// C[row, col] = sum_k xb[row,k] * WT[col,k] + bqkv[col]
// GEMM schedule = EXACT round-4/round-9 structure (twice-reproduced 250us; the
// 8-phase port was falsified 3x, counted-ring variants 2x, 2-block/CU 1x,
// 32x32 shape 1x, persistent mega-fusion 1x — schedule frozen).
// Paired k/v partition for by>=4: block owns matched k-slice K0..K0+127 AND
// v-slice V0..V0+127; epilogue stores p[t,d] = (k+bk)*(v+bv) bf16 (64 MB)
// instead of k,v (128 MB); kv_reduce reads half the bytes.

#define SLOT(RING, SRING, STG, VM) do {                                           \
    short8 bF[4], aF[8];                                                          \
    _Pragma("unroll")                                                             \
    for (int nt = 0; nt < 4; ++nt)                                                \
        bF[nt] = *reinterpret_cast<const short8*>(&b_sh[RING][bRd + nt * 512]);   \
    _Pragma("unroll")                                                             \
    for (int mi = 0; mi < 8; ++mi)                                                \
        aF[mi] = *reinterpret_cast<const short8*>(&a_sh[RING][aRd + mi * 512]);   \
    if (STG) {                                                                    \
        GLL16(aPtr0, &a_sh[SRING][aDst0]); GLL16(aPtr1, &a_sh[SRING][aDst1]);     \
        GLL16(bPtr0, &b_sh[SRING][aDst0]); GLL16(bPtr1, &b_sh[SRING][aDst1]);     \
        aPtr0 += 32; aPtr1 += 32; bPtr0 += 32; bPtr1 += 32;                       \
    }                                                                             \
    _Pragma("unroll")                                                             \
    for (int mi = 0; mi < 8; ++mi)                                                \
        _Pragma("unroll")                                                         \
        for (int nt = 0; nt < 4; ++nt)                                            \
            acc[mi][nt] = __builtin_amdgcn_mfma_f32_16x16x32_bf16(                \
                aF[mi], bF[nt], acc[mi][nt], 0, 0, 0);                            \
    __builtin_amdgcn_sched_barrier(0);                                            \
    if ((VM) == 8)      asm volatile("s_waitcnt vmcnt(8)" ::: "memory");          \
    else if ((VM) == 4) asm volatile("s_waitcnt vmcnt(4)" ::: "memory");          \
    else if ((VM) == 0) asm volatile("s_waitcnt vmcnt(0)" ::: "memory");          \
    __builtin_amdgcn_s_barrier();                                                 \
} while (0)

__global__ __launch_bounds__(512, 1)
void gemm_k(const u16* __restrict__ xb, const u16* __restrict__ WT,
            const float* __restrict__ bqkv,
            u16* __restrict__ qb, u16* __restrict__ pb,
            float* __restrict__ qssq, float* __restrict__ kssq)
{
    // 4-slot ring: each slot 256 rows x 32 k (u16) = 16 KB per operand; 128 KiB total
    __shared__ __align__(16) u16 a_sh[4][8192];
    __shared__ __align__(16) u16 b_sh[4][8192];

    const int tid  = threadIdx.x;
    const int lane = tid & 63;
    const int w    = tid >> 6;      // wave 0..7
    const int l15  = lane & 15;
    const int quad = lane >> 4;     // 0..3
    const int wm   = w >> 2;        // 0..1  (M half)
    const int wn   = w & 3;         // 0..3  (N quarter)

    // bijective XCD swizzle: 1536 blocks, 192 contiguous (bx,by) per XCD
    const int flat = blockIdx.x;
    const int swz  = (flat & 7) * 192 + (flat >> 3);
    const int bx   = swz & 127;     // 0..127 (M)
    const int by   = swz >> 7;      // 0..11  (N)
    const int r0   = bx * 256;
    const int c0   = by * 256;
    const int K0   = 1024 + (by - 4) * 128;   // k-col base (by>=4)
    const int V0   = K0 + 1024;               // matched v-col base

    // ---- staging addresses ----
    const int row0 = w * 32 + (lane >> 2);
    const int gsrc = (lane & 3) ^ ((lane >> 3) & 3);   // same for i=0,1 (rows differ by 16)
    const u16* aPtr0 = xb + (size_t)(r0 + row0) * D_DIM + gsrc * 8;
    const u16* aPtr1 = xb + (size_t)(r0 + row0 + 16) * D_DIM + gsrc * 8;
    int srcB0, srcB1;
    if (by < 4) {
        srcB0 = c0 + row0;
        srcB1 = c0 + row0 + 16;
    } else {
        int rB0 = row0,      wn0 = rB0 >> 6, cs0 = rB0 & 63;
        int rB1 = row0 + 16, wn1 = rB1 >> 6, cs1 = rB1 & 63;
        srcB0 = (cs0 < 32) ? (K0 + wn0 * 32 + cs0) : (V0 + wn0 * 32 + cs0 - 32);
        srcB1 = (cs1 < 32) ? (K0 + wn1 * 32 + cs1) : (V0 + wn1 * 32 + cs1 - 32);
    }
    const u16* bPtr0 = WT + (size_t)srcB0 * D_DIM + gsrc * 8;
    const u16* bPtr1 = WT + (size_t)srcB1 * D_DIM + gsrc * 8;
    const int aDst0 = w * 1024;          // wave-uniform linear LDS dest (u16 idx)
    const int aDst1 = w * 1024 + 512;

    // ---- fragment read offsets (u16 index within a slot) ----
    const int gq  = (quad ^ ((l15 >> 1) & 3)) * 8;
    const int aRd = (wm * 128 + l15) * 32 + gq;      // + mi*512, mi=0..7
    const int bRd = (wn * 64 + l15) * 32 + gq;       // + nt*512, nt=0..3

    f32x4 acc[8][4];
    #pragma unroll
    for (int mi = 0; mi < 8; ++mi)
        #pragma unroll
        for (int nt = 0; nt < 4; ++nt) acc[mi][nt] = (f32x4)(0.0f);

    // ---- prologue: stage slots 0,1,2 ----
    GLL16(aPtr0, &a_sh[0][aDst0]); GLL16(aPtr1, &a_sh[0][aDst1]);
    GLL16(bPtr0, &b_sh[0][aDst0]); GLL16(bPtr1, &b_sh[0][aDst1]);
    aPtr0 += 32; aPtr1 += 32; bPtr0 += 32; bPtr1 += 32;
    GLL16(aPtr0, &a_sh[1][aDst0]); GLL16(aPtr1, &a_sh[1][aDst1]);
    GLL16(bPtr0, &b_sh[1][aDst0]); GLL16(bPtr1, &b_sh[1][aDst1]);
    aPtr0 += 32; aPtr1 += 32; bPtr0 += 32; bPtr1 += 32;
    GLL16(aPtr0, &a_sh[2][aDst0]); GLL16(aPtr1, &a_sh[2][aDst1]);
    GLL16(bPtr0, &b_sh[2][aDst0]); GLL16(bPtr1, &b_sh[2][aDst1]);
    aPtr0 += 32; aPtr1 += 32; bPtr0 += 32; bPtr1 += 32;
    asm volatile("s_waitcnt vmcnt(8)" ::: "memory");   // slot 0 resident (own loads)
    __builtin_amdgcn_s_barrier();                      // ... for all waves

    // ---- main loop: slots 0..27; slot s reads ring s&3, stages ring (s+3)&3 ----
    #pragma unroll 1
    for (int it = 0; it < 7; ++it) {
        SLOT(0, 3, 1, 8);
        SLOT(1, 0, 1, 8);
        SLOT(2, 1, 1, 8);
        SLOT(3, 2, 1, 8);
    }
    // ---- tail: slots 28..31 ----
    SLOT(0, 3, 1, 8);    // 28: stages slot 31; end-wait certifies slot 29
    SLOT(1, 0, 0, 4);    // 29: end-wait certifies slot 30
    SLOT(2, 0, 0, 0);    // 30: end-wait certifies slot 31
    SLOT(3, 0, 0, -1);   // 31

    if (by < 4) {
        // ---- q path: bias, qssq, store qb ----
        float bcol[4];
        #pragma unroll
        for (int nt = 0; nt < 4; ++nt)
            bcol[nt] = bqkv[c0 + wn * 64 + nt * 16 + l15];
        #pragma unroll
        for (int mi = 0; mi < 8; ++mi)
            #pragma unroll
            for (int nt = 0; nt < 4; ++nt)
                #pragma unroll
                for (int rg = 0; rg < 4; ++rg) acc[mi][nt][rg] += bcol[nt];

        #pragma unroll
        for (int mi = 0; mi < 8; ++mi)
            #pragma unroll
            for (int rg = 0; rg < 4; ++rg) {
                float s = acc[mi][0][rg] * acc[mi][0][rg]
                        + acc[mi][1][rg] * acc[mi][1][rg]
                        + acc[mi][2][rg] * acc[mi][2][rg]
                        + acc[mi][3][rg] * acc[mi][3][rg];
                #pragma unroll
                for (int m = 1; m < 16; m <<= 1) s += __shfl_xor(s, m, 16);
                if (l15 == 0)
                    atomicAdd(&qssq[r0 + wm * 128 + mi * 16 + quad * 4 + rg], s);
            }

        #pragma unroll
        for (int mi = 0; mi < 8; ++mi)
            #pragma unroll
            for (int nt = 0; nt < 4; ++nt) {
                int col = c0 + wn * 64 + nt * 16 + l15;
                #pragma unroll
                for (int rg = 0; rg < 4; ++rg) {
                    int row = r0 + wm * 128 + mi * 16 + quad * 4 + rg;
                    qb[(size_t)row * 1024 + col] = f2bf(acc[mi][nt][rg]);
                }
            }
    } else {
        // ---- paired k/v path: bias, kssq (k frags), store p = k*v ----
        float bcol[4];
        #pragma unroll
        for (int nt = 0; nt < 4; ++nt)
            bcol[nt] = (nt < 2) ? bqkv[K0 + wn * 32 + nt * 16 + l15]
                                : bqkv[V0 + wn * 32 + (nt - 2) * 16 + l15];
        #pragma unroll
        for (int mi = 0; mi < 8; ++mi)
            #pragma unroll
            for (int nt = 0; nt < 4; ++nt)
                #pragma unroll
                for (int rg = 0; rg < 4; ++rg) acc[mi][nt][rg] += bcol[nt];

        #pragma unroll
        for (int mi = 0; mi < 8; ++mi)
            #pragma unroll
            for (int rg = 0; rg < 4; ++rg) {
                float s = acc[mi][0][rg] * acc[mi][0][rg]
                        + acc[mi][1][rg] * acc[mi][1][rg];
                #pragma unroll
                for (int m = 1; m < 16; m <<= 1) s += __shfl_xor(s, m, 16);
                if (l15 == 0)
                    atomicAdd(&kssq[r0 + wm * 128 + mi * 16 + quad * 4 + rg], s);
            }

        #pragma unroll
        for (int mi = 0; mi < 8; ++mi)
            #pragma unroll
            for (int ntp = 0; ntp < 2; ++ntp) {
                int col = (by - 4) * 128 + wn * 32 + ntp * 16 + l15;
                #pragma unroll
                for (int rg = 0; rg < 4; ++rg) {
                    int row = r0 + wm * 128 + mi * 16 + quad * 4 + rg;
                    pb[(size_t)row * 1024 + col] =
                        f2bf(acc[mi][ntp][rg] * acc[mi][ntp + 2][rg]);
                }
            }
    }
}

// ---------------- Kernel 3: kv[b,d] = sum_t p[t,d]*rsqrt(kssq[t]) ----------------
__global__ void kv_reduce(const u16* __restrict__ pb, const float* __restrict__ kssq,
                          float* __restrict__ kv)
{
    int d  = threadIdx.x * 8;                  // 128 threads cover 1024 d
    int b  = blockIdx.y;                       // 0..3
    int t0 = blockIdx.x * 64;                  // 128 t-chunks of 64 rows
    float a[8];
    #pragma unroll
    for (int e = 0; e < 8; ++e) a[e] = 0.0f;
    for (int r = 0; r < 64; ++r) {
        int row = b * T_DIM + t0 + r;
        float kin = rsqrtf(kssq[row]);
        short8 p8 = *reinterpret_cast<const short8*>(pb + (size_t)row * 1024 + d);
        #pragma unroll
        for (int e = 0; e < 8; ++e)
            a[e] += bf2f((u16)p8[e]) * kin;
    }
    #pragma unroll
    for (int e = 0; e < 8; ++e)
        atomicAdd(&kv[b * D_DIM + d + e], a[e]);
}

// ---------------- Kernel 4: out = q*rsqrt(qssq)*kv*scale + bias (fp32) ----------------
__global__ void finalize(const u16* __restrict__ qb, const float* __restrict__ qssq,
                         const float* __restrict__ kv, const float* __restrict__ scale,
                         const float* __restrict__ bias, float* __restrict__ out)
{
    size_t idx = (size_t)blockIdx.x * 256 + threadIdx.x;   // vec8 index
    int row = (int)(idx >> 7);
    int dv  = ((int)idx & 127) * 8;
    int b   = row >> 13;
    float qi = rsqrtf(qssq[row]);
    short8 qv = *reinterpret_cast<const short8*>(qb + (size_t)row * D_DIM + dv);
    const float* kvp = kv + b * D_DIM + dv;
    const float* sp  = scale + dv;
    const float* bp  = bias + dv;
    float4 o0, o1;
    o0.x = bf2f((u16)qv[0]) * qi * kvp[0] * sp[0] + bp[0];
    o0.y = bf2f((u16)qv[1]) * qi * kvp[1] * sp[1] + bp[1];
    o0.z = bf2f((u16)qv[2]) * qi * kvp[2] * sp[2] + bp[2];
    o0.w = bf2f((u16)qv[3]) * qi * kvp[3] * sp[3] + bp[3];
    o1.x = bf2f((u16)qv[4]) * qi * kvp[4] * sp[4] + bp[4];
    o1.y = bf2f((u16)qv[5]) * qi * kvp[5] * sp[5] + bp[5];
    o1.z = bf2f((u16)qv[6]) * qi * kvp[6] * sp[6] + bp[6];
    o1.w = bf2f((u16)qv[7]) * qi * kvp[7] * sp[7] + bp[7];
    float* op = out + (size_t)row * D_DIM + dv;
    *reinterpret_cast<float4*>(op)     = o0;
    *reinterpret_cast<float4*>(op + 4) = o1;
}

extern "C" void kernel_launch(void* const* d_in, const int* in_sizes, int n_in,
                              void* d_out, int out_size, void* d_ws, size_t ws_size,
                              hipStream_t stream) {
    const float* x     = (const float*)d_in[0];
    const float* W     = (const float*)d_in[1];
    const float* bqkv  = (const float*)d_in[2];
    const float* scale = (const float*)d_in[3];
    const float* bias  = (const float*)d_in[4];
    float* out = (float*)d_out;

    // d_out doubles as scratch until finalize: xb (64 MB) + WT (6 MB) < 128 MB
    u16* xb = (u16*)d_out;
    u16* WT = (u16*)((char*)d_out + 67108864);

    char* ws = (char*)d_ws;
    u16*   qb   = (u16*)ws;                         //  67,108,864 B
    u16*   pb   = (u16*)(ws + 67108864);            //  67,108,864 B (k*v products)
    float* qssq = (float*)(ws + 134217728);         //     131,072 B
    float* kssq = (float*)(ws + 134348800);         //     131,072 B
    float* kv   = (float*)(ws + 134479872);         //      16,384 B
    // qssq|kssq|kv contiguous: 278,528 B = 68 blocks x 256 thr x 16 B zeroed in prep

    prep      <<<dim3(16384 + 3072 + 68), dim3(256), 0, stream>>>(x, xb, W, WT, qssq);
    gemm_k    <<<dim3(1536), dim3(512), 0, stream>>>(xb, WT, bqkv, qb, pb, qssq, kssq);
    kv_reduce <<<dim3(T_DIM / 64, 4), dim3(128), 0, stream>>>(pb, kssq, kv);
    finalize  <<<dim3(ROWS * (D_DIM / 8) / 256), dim3(256), 0, stream>>>(qb, qssq, kv, scale, bias, out);
}